// Round 12
// baseline (1425.697 us; speedup 1.0000x reference)
//
#include <hip/hip_runtime.h>
#include <hip/hip_bf16.h>
#include <math.h>

// ResGatedGraphConv x3 + logit head for MI355X.
// R11 (resubmit of R9 — infra timeouts R10/R11): 16-edge load phase pinned
// with sched_barrier(0), q/v channel-interleaved (one dwordx2 gather per
// edge per lane). R8 post-mortem: VGPR=24 proved compiler serialized the
// 4-edge pipeline.

#define D_CH 64
#define E_CH 16

// ---- prep: zero degree array; block 0 also detects int64 vs int32 ----
__global__ void k_prep(const unsigned int* __restrict__ ei, int* __restrict__ flag,
                       int* __restrict__ deg, int N, int nsamp) {
  int i = blockIdx.x * blockDim.x + threadIdx.x;
  if (i < N) deg[i] = 0;
  if (blockIdx.x == 0) {
    unsigned int acc = 0;
    for (int s = threadIdx.x; s < nsamp; s += blockDim.x) acc |= ei[2 * s + 1];
    int nz = __syncthreads_or(acc != 0u);
    if (threadIdx.x == 0) flag[0] = nz ? 0 : 1;
  }
}

// ---- normalize edge_index + histogram degrees (fused) ----
__global__ void k_normhist(const void* __restrict__ ei, const int* __restrict__ flag,
                           int* __restrict__ src, int* __restrict__ dstA,
                           int* __restrict__ deg, int E) {
  int e = blockIdx.x * blockDim.x + threadIdx.x;
  if (e >= E) return;
  int s, d;
  if (flag[0]) {
    const long long* p = (const long long*)ei;
    s = (int)p[e];
    d = (int)p[E + e];
  } else {
    const int* p = (const int*)ei;
    s = p[e];
    d = p[E + e];
  }
  src[e] = s;
  dstA[e] = d;
  atomicAdd(&deg[d], 1);
}

// ---- scan part 1: per-1024-chunk sums ----
__global__ void k_scanpart(const int* __restrict__ deg, int* __restrict__ partial, int N) {
  __shared__ int wsum[4];
  int tid = threadIdx.x, lane = tid & 63, w = tid >> 6;
  int i0 = blockIdx.x * 1024 + tid * 4;
  int4 v = make_int4(0, 0, 0, 0);
  if (i0 + 3 < N) {
    v = *(const int4*)(deg + i0);
  } else {
    if (i0 < N) v.x = deg[i0];
    if (i0 + 1 < N) v.y = deg[i0 + 1];
    if (i0 + 2 < N) v.z = deg[i0 + 2];
  }
  int s = v.x + v.y + v.z + v.w;
#pragma unroll
  for (int m = 32; m; m >>= 1) s += __shfl_xor(s, m);
  if (lane == 0) wsum[w] = s;
  __syncthreads();
  if (tid == 0) partial[blockIdx.x] = wsum[0] + wsum[1] + wsum[2] + wsum[3];
}

// ---- scan part 2: exclusive scan of chunk partials (<=128 chunks fast path) ----
__global__ void k_scanroot(int* __restrict__ partial, int* __restrict__ offsets,
                           int NB, int N) {
  if (NB <= 128) {
    int lane = threadIdx.x;
    int a = (lane < NB) ? partial[lane] : 0;
    int b = (lane + 64 < NB) ? partial[lane + 64] : 0;
    int sa = a, sb = b;
#pragma unroll
    for (int off = 1; off < 64; off <<= 1) {
      int t = __shfl_up(sa, off);
      if (lane >= off) sa += t;
      int u = __shfl_up(sb, off);
      if (lane >= off) sb += u;
    }
    int atot = __shfl(sa, 63);
    sb += atot;
    int tot = __shfl(sb, 63);
    if (lane < NB) partial[lane] = sa - a;
    if (lane + 64 < NB) partial[lane + 64] = sb - b;
    if (lane == 0) offsets[N] = tot;
  } else {
    if (threadIdx.x == 0) {
      int run = 0;
      for (int bI = 0; bI < NB; ++bI) {
        int vv = partial[bI];
        partial[bI] = run;
        run += vv;
      }
      offsets[N] = run;
    }
  }
}

// ---- scan part 3: local exclusive scan + base -> offsets & cursor ----
__global__ void k_scanapply(const int* __restrict__ deg, const int* __restrict__ partial,
                            int* __restrict__ offsets, int* __restrict__ cursor, int N) {
  __shared__ int wsum[4];
  int tid = threadIdx.x, lane = tid & 63, w = tid >> 6;
  int i0 = blockIdx.x * 1024 + tid * 4;
  int4 v = make_int4(0, 0, 0, 0);
  if (i0 + 3 < N) {
    v = *(const int4*)(deg + i0);
  } else {
    if (i0 < N) v.x = deg[i0];
    if (i0 + 1 < N) v.y = deg[i0 + 1];
    if (i0 + 2 < N) v.z = deg[i0 + 2];
  }
  int ts = v.x + v.y + v.z + v.w;
  int s = ts;
#pragma unroll
  for (int off = 1; off < 64; off <<= 1) {
    int t = __shfl_up(s, off);
    if (lane >= off) s += t;
  }
  if (lane == 63) wsum[w] = s;
  __syncthreads();
  int wb = 0;
#pragma unroll
  for (int x = 0; x < 4; ++x)
    if (x < w) wb += wsum[x];
  int excl = s - ts + wb + partial[blockIdx.x];
  int o0 = excl, o1 = o0 + v.x, o2 = o1 + v.y, o3 = o2 + v.z;
  if (i0 + 3 < N) {
    int4 o = make_int4(o0, o1, o2, o3);
    *(int4*)(offsets + i0) = o;
    *(int4*)(cursor + i0) = o;
  } else {
    if (i0 < N) { offsets[i0] = o0; cursor[i0] = o0; }
    if (i0 + 1 < N) { offsets[i0 + 1] = o1; cursor[i0 + 1] = o1; }
    if (i0 + 2 < N) { offsets[i0 + 2] = o2; cursor[i0 + 2] = o2; }
  }
}

// ---- scatter edges into CSR (packed int2: src node, edge id) ----
__global__ void k_scatter(const int* __restrict__ src, const int* __restrict__ dstA,
                          int* __restrict__ cursor, int2* __restrict__ je, int E) {
  int e = blockIdx.x * blockDim.x + threadIdx.x;
  if (e >= E) return;
  int d = dstA[e];
  int p = atomicAdd(&cursor[d], 1);
  je[p] = make_int2(src[e], e);
}

__device__ __forceinline__ float bcastf(float v, int srclane) {
  return __int_as_float(__builtin_amdgcn_readlane(__float_as_int(v), srclane));
}

// ---- node linear: outa = hin@Wa + ba ; outb = hin@Wb + bb ----
// Output index: i*ostride + astep*lane for both -> allows channel-interleaved
// q/v layout (astep=2, outb=outa+1).
__global__ __launch_bounds__(256, 1) void k_nodelin(
    const float* __restrict__ hin, const float* __restrict__ Wa,
    const float* __restrict__ ba, const float* __restrict__ Wb,
    const float* __restrict__ bb, float* __restrict__ outa, float* __restrict__ outb,
    int ostride, int astep, int N) {
  int lane = threadIdx.x & 63;
  int wave = blockIdx.x * (blockDim.x >> 6) + (threadIdx.x >> 6);
  int nwaves = gridDim.x * (blockDim.x >> 6);
  float wa[64], wb[64];
#pragma unroll
  for (int c = 0; c < 64; ++c) {
    wa[c] = Wa[c * 64 + lane];
    wb[c] = Wb[c * 64 + lane];
  }
  float bav = ba[lane], bbv = bb[lane];
  for (int i = wave; i < N; i += nwaves) {
    float h = hin[(size_t)i * 64 + lane];
    float a = bav, b = bbv;
#pragma unroll
    for (int c = 0; c < 64; ++c) {
      float hc = bcastf(h, c);
      a = fmaf(hc, wa[c], a);
      b = fmaf(hc, wb[c], b);
    }
    outa[(size_t)i * ostride + astep * lane] = a;
    outb[(size_t)i * ostride + astep * lane] = b;
  }
}

// ---- edge gather + gate + aggregate + skip + elu (+ output fusion) ----
// qv layout: row j = [q0,v0,q1,v1,...], stride 128; lane loads float2 at 2*lane.
template <int MODE>
__global__ __launch_bounds__(256, 4) void k_edge(
    const int* __restrict__ offsets, const int2* __restrict__ je,
    const float* __restrict__ kk, const float* __restrict__ qv,
    const float* __restrict__ base, const float* __restrict__ ea,
    const float* __restrict__ We, const float* __restrict__ be,
    float* __restrict__ hnext, float* __restrict__ dout,
    const float* __restrict__ Wl, const float* __restrict__ bl, int N) {
  int lane = threadIdx.x & 63;
  int wave = blockIdx.x * (blockDim.x >> 6) + (threadIdx.x >> 6);
  int nwaves = gridDim.x * (blockDim.x >> 6);
  float we[16];
#pragma unroll
  for (int c = 0; c < 16; ++c) we[c] = We[c * 64 + lane];
  float bev = be[lane];
  float wl = (MODE == 2) ? Wl[lane] : 0.f;
  float bl0 = (MODE == 2) ? bl[0] : 0.f;
  for (int i = wave; i < N; i += nwaves) {
    float ki = kk[(size_t)i * 64 + lane] + bev;  // fold be into k_i
    float acc = base[(size_t)i * 64 + lane];
    int p0 = __builtin_amdgcn_readfirstlane(offsets[i]);
    int p1 = __builtin_amdgcn_readfirstlane(offsets[i + 1]);
    for (int pb = p0; pb < p1; pb += 64) {
      int m = p1 - pb;
      if (m > 64) m = 64;
      // cooperative CSR metadata load: one coalesced int2 per lane covers 64 edges
      int idx = pb + ((lane < m) ? lane : 0);
      int2 meta = je[idx];
      int t = 0;
      for (; t + 16 <= m; t += 16) {
        float2 qvr[16];
        int eidv[16];
        // ---- load phase: 16 gathers issued back-to-back ----
#pragma unroll
        for (int u = 0; u < 16; ++u) {
          int j = __builtin_amdgcn_readlane(meta.x, t + u);
          eidv[u] = __builtin_amdgcn_readlane(meta.y, t + u);
          qvr[u] = *(const float2*)(qv + (size_t)j * 128 + 2 * lane);
        }
        // pin: compute (and these loads) may not cross this point
        __builtin_amdgcn_sched_barrier(0);
        // ---- compute phase ----
#pragma unroll
        for (int u = 0; u < 16; ++u) {
          const float4* ap = (const float4*)(ea + (size_t)eidv[u] * E_CH);
          float4 a0 = ap[0], a1 = ap[1], a2 = ap[2], a3 = ap[3];
          float ev = 0.f;
          ev = fmaf(a0.x, we[0], ev);   ev = fmaf(a0.y, we[1], ev);
          ev = fmaf(a0.z, we[2], ev);   ev = fmaf(a0.w, we[3], ev);
          ev = fmaf(a1.x, we[4], ev);   ev = fmaf(a1.y, we[5], ev);
          ev = fmaf(a1.z, we[6], ev);   ev = fmaf(a1.w, we[7], ev);
          ev = fmaf(a2.x, we[8], ev);   ev = fmaf(a2.y, we[9], ev);
          ev = fmaf(a2.z, we[10], ev);  ev = fmaf(a2.w, we[11], ev);
          ev = fmaf(a3.x, we[12], ev);  ev = fmaf(a3.y, we[13], ev);
          ev = fmaf(a3.z, we[14], ev);  ev = fmaf(a3.w, we[15], ev);
          float g = ki + qvr[u].x + ev;
          g = 1.0f / (1.0f + __expf(-g));
          acc = fmaf(g, qvr[u].y, acc);
        }
      }
      // tail: one edge at a time
      for (; t < m; ++t) {
        int j = __builtin_amdgcn_readlane(meta.x, t);
        int eid = __builtin_amdgcn_readlane(meta.y, t);
        float2 qvv = *(const float2*)(qv + (size_t)j * 128 + 2 * lane);
        const float4* ap = (const float4*)(ea + (size_t)eid * E_CH);
        float4 a0 = ap[0], a1 = ap[1], a2 = ap[2], a3 = ap[3];
        float ev = 0.f;
        ev = fmaf(a0.x, we[0], ev);   ev = fmaf(a0.y, we[1], ev);
        ev = fmaf(a0.z, we[2], ev);   ev = fmaf(a0.w, we[3], ev);
        ev = fmaf(a1.x, we[4], ev);   ev = fmaf(a1.y, we[5], ev);
        ev = fmaf(a1.z, we[6], ev);   ev = fmaf(a1.w, we[7], ev);
        ev = fmaf(a2.x, we[8], ev);   ev = fmaf(a2.y, we[9], ev);
        ev = fmaf(a2.z, we[10], ev);  ev = fmaf(a2.w, we[11], ev);
        ev = fmaf(a3.x, we[12], ev);  ev = fmaf(a3.y, we[13], ev);
        ev = fmaf(a3.z, we[14], ev);  ev = fmaf(a3.w, we[15], ev);
        float g = ki + qvv.x + ev;
        g = 1.0f / (1.0f + __expf(-g));
        acc = fmaf(g, qvv.y, acc);
      }
    }
    float r = (acc > 0.f) ? acc : expm1f(acc);  // elu
    if (MODE == 0) {
      hnext[(size_t)i * 64 + lane] = r;
    } else if (MODE == 1) {
      hnext[(size_t)i * 64 + lane] = r;
      dout[(size_t)N + (size_t)i * 64 + lane] = r;       // feat block
      dout[(size_t)N * 65 + (size_t)i * 65 + lane] = r;  // concat block
    } else {
      float dot = r * wl;
#pragma unroll
      for (int m2 = 32; m2 >= 1; m2 >>= 1) dot += __shfl_xor(dot, m2);
      float logit = dot + bl0;
      if (lane == 0) {
        dout[i] = 1.0f / (1.0f + __expf(-logit));
        dout[(size_t)N * 65 + (size_t)i * 65 + 64] = logit;  // raw logit col
      }
    }
  }
}

extern "C" void kernel_launch(void* const* d_in, const int* in_sizes, int n_in,
                              void* d_out, int out_size, void* d_ws, size_t ws_size,
                              hipStream_t stream) {
  const float* x   = (const float*)d_in[0];
  const void*  ei  = d_in[1];
  const float* ea  = (const float*)d_in[2];
  const float* Wk  = (const float*)d_in[3];
  const float* bk  = (const float*)d_in[4];
  const float* Wq  = (const float*)d_in[5];
  const float* bq  = (const float*)d_in[6];
  const float* Wv  = (const float*)d_in[7];
  const float* bv  = (const float*)d_in[8];
  const float* We  = (const float*)d_in[9];
  const float* be  = (const float*)d_in[10];
  const float* Ws  = (const float*)d_in[11];
  const float* bia = (const float*)d_in[12];
  const float* Wl  = (const float*)d_in[13];
  const float* bl  = (const float*)d_in[14];
  int N = in_sizes[0] / D_CH;
  int E = in_sizes[2] / E_CH;
  int NB = (N + 1023) / 1024;

  char* w = (char*)d_ws;
  auto alloc = [&](size_t bytes) -> char* {
    char* r = w;
    w += (bytes + 255) & ~(size_t)255;
    return r;
  };
  int* flag     = (int*)alloc(16);
  int* src      = (int*)alloc((size_t)E * 4);
  int* dstA     = (int*)alloc((size_t)E * 4);
  int* deg      = (int*)alloc((size_t)N * 4);
  int* partial  = (int*)alloc((size_t)NB * 4);
  int* offsets  = (int*)alloc((size_t)(N + 1) * 4);
  int* cursor   = (int*)alloc((size_t)N * 4);
  int2* je      = (int2*)alloc((size_t)E * 8);
  float* kk     = (float*)alloc((size_t)N * D_CH * 4);
  float* qv     = (float*)alloc((size_t)N * 128 * 4);
  float* baseb  = (float*)alloc((size_t)N * D_CH * 4);
  float* h1     = (float*)alloc((size_t)N * D_CH * 4);
  float* feat   = (float*)alloc((size_t)N * D_CH * 4);
  float* dout   = (float*)d_out;

  int gE = (E + 255) / 256;
  int gN = (N + 255) / 256;

  k_prep<<<gN, 256, 0, stream>>>((const unsigned int*)ei, flag, deg, N, 8192);
  k_normhist<<<gE, 256, 0, stream>>>(ei, flag, src, dstA, deg, E);
  k_scanpart<<<NB, 256, 0, stream>>>(deg, partial, N);
  k_scanroot<<<1, 64, 0, stream>>>(partial, offsets, NB, N);
  k_scanapply<<<NB, 256, 0, stream>>>(deg, partial, offsets, cursor, N);
  k_scatter<<<gE, 256, 0, stream>>>(src, dstA, cursor, je, E);

  const float* hin = x;
  for (int l = 0; l < 3; ++l) {
    const float* Wk_l = Wk + (size_t)l * 4096;
    const float* bk_l = bk + (size_t)l * 64;
    const float* Wq_l = Wq + (size_t)l * 4096;
    const float* bq_l = bq + (size_t)l * 64;
    const float* Wv_l = Wv + (size_t)l * 4096;
    const float* bv_l = bv + (size_t)l * 64;
    const float* We_l = We + (size_t)l * 1024;
    const float* be_l = be + (size_t)l * 64;
    const float* Ws_l = Ws + (size_t)l * 4096;
    const float* bi_l = bia + (size_t)l * 64;

    // k and skip-base (stride 64, step 1); q and v channel-interleaved in qv
    // (stride 128, step 2, v at +1)
    k_nodelin<<<1024, 256, 0, stream>>>(hin, Wk_l, bk_l, Ws_l, bi_l, kk, baseb,
                                        64, 1, N);
    k_nodelin<<<1024, 256, 0, stream>>>(hin, Wq_l, bq_l, Wv_l, bv_l, qv, qv + 1,
                                        128, 2, N);
    if (l == 0) {
      k_edge<0><<<2048, 256, 0, stream>>>(offsets, je, kk, qv, baseb, ea, We_l, be_l,
                                          h1, dout, Wl, bl, N);
      hin = h1;
    } else if (l == 1) {
      k_edge<1><<<2048, 256, 0, stream>>>(offsets, je, kk, qv, baseb, ea, We_l, be_l,
                                          feat, dout, Wl, bl, N);
      hin = feat;
    } else {
      k_edge<2><<<2048, 256, 0, stream>>>(offsets, je, kk, qv, baseb, ea, We_l, be_l,
                                          h1, dout, Wl, bl, N);
    }
  }
}

// Round 13
// 1350.108 us; speedup vs baseline: 1.0560x; 1.0560x over previous
//
#include <hip/hip_runtime.h>
#include <hip/hip_bf16.h>
#include <math.h>

// ResGatedGraphConv x3 + logit head for MI355X.
// R12: inline-asm 8-deep gather pipeline (asm volatile global_load_dwordx2
// cannot be sunk/rematerialized), waitcnt with "+v" result operands to pin
// consumers, zero-masked clamp removes the serial per-node tail.
// R9 post-mortem: sched_barrier alone was defeated by load rematerialization
// (VGPR=36, k_edge 299us). R8: VGPR=24, 240us, ~900cyc serial chain/edge.

#define D_CH 64
#define E_CH 16

// ---- prep: zero degree array; block 0 also detects int64 vs int32 ----
__global__ void k_prep(const unsigned int* __restrict__ ei, int* __restrict__ flag,
                       int* __restrict__ deg, int N, int nsamp) {
  int i = blockIdx.x * blockDim.x + threadIdx.x;
  if (i < N) deg[i] = 0;
  if (blockIdx.x == 0) {
    unsigned int acc = 0;
    for (int s = threadIdx.x; s < nsamp; s += blockDim.x) acc |= ei[2 * s + 1];
    int nz = __syncthreads_or(acc != 0u);
    if (threadIdx.x == 0) flag[0] = nz ? 0 : 1;
  }
}

// ---- normalize edge_index + histogram degrees (fused) ----
__global__ void k_normhist(const void* __restrict__ ei, const int* __restrict__ flag,
                           int* __restrict__ src, int* __restrict__ dstA,
                           int* __restrict__ deg, int E) {
  int e = blockIdx.x * blockDim.x + threadIdx.x;
  if (e >= E) return;
  int s, d;
  if (flag[0]) {
    const long long* p = (const long long*)ei;
    s = (int)p[e];
    d = (int)p[E + e];
  } else {
    const int* p = (const int*)ei;
    s = p[e];
    d = p[E + e];
  }
  src[e] = s;
  dstA[e] = d;
  atomicAdd(&deg[d], 1);
}

// ---- scan part 1: per-1024-chunk sums ----
__global__ void k_scanpart(const int* __restrict__ deg, int* __restrict__ partial, int N) {
  __shared__ int wsum[4];
  int tid = threadIdx.x, lane = tid & 63, w = tid >> 6;
  int i0 = blockIdx.x * 1024 + tid * 4;
  int4 v = make_int4(0, 0, 0, 0);
  if (i0 + 3 < N) {
    v = *(const int4*)(deg + i0);
  } else {
    if (i0 < N) v.x = deg[i0];
    if (i0 + 1 < N) v.y = deg[i0 + 1];
    if (i0 + 2 < N) v.z = deg[i0 + 2];
  }
  int s = v.x + v.y + v.z + v.w;
#pragma unroll
  for (int m = 32; m; m >>= 1) s += __shfl_xor(s, m);
  if (lane == 0) wsum[w] = s;
  __syncthreads();
  if (tid == 0) partial[blockIdx.x] = wsum[0] + wsum[1] + wsum[2] + wsum[3];
}

// ---- scan part 2: exclusive scan of chunk partials (<=128 chunks fast path) ----
__global__ void k_scanroot(int* __restrict__ partial, int* __restrict__ offsets,
                           int NB, int N) {
  if (NB <= 128) {
    int lane = threadIdx.x;
    int a = (lane < NB) ? partial[lane] : 0;
    int b = (lane + 64 < NB) ? partial[lane + 64] : 0;
    int sa = a, sb = b;
#pragma unroll
    for (int off = 1; off < 64; off <<= 1) {
      int t = __shfl_up(sa, off);
      if (lane >= off) sa += t;
      int u = __shfl_up(sb, off);
      if (lane >= off) sb += u;
    }
    int atot = __shfl(sa, 63);
    sb += atot;
    int tot = __shfl(sb, 63);
    if (lane < NB) partial[lane] = sa - a;
    if (lane + 64 < NB) partial[lane + 64] = sb - b;
    if (lane == 0) offsets[N] = tot;
  } else {
    if (threadIdx.x == 0) {
      int run = 0;
      for (int bI = 0; bI < NB; ++bI) {
        int vv = partial[bI];
        partial[bI] = run;
        run += vv;
      }
      offsets[N] = run;
    }
  }
}

// ---- scan part 3: local exclusive scan + base -> offsets & cursor ----
__global__ void k_scanapply(const int* __restrict__ deg, const int* __restrict__ partial,
                            int* __restrict__ offsets, int* __restrict__ cursor, int N) {
  __shared__ int wsum[4];
  int tid = threadIdx.x, lane = tid & 63, w = tid >> 6;
  int i0 = blockIdx.x * 1024 + tid * 4;
  int4 v = make_int4(0, 0, 0, 0);
  if (i0 + 3 < N) {
    v = *(const int4*)(deg + i0);
  } else {
    if (i0 < N) v.x = deg[i0];
    if (i0 + 1 < N) v.y = deg[i0 + 1];
    if (i0 + 2 < N) v.z = deg[i0 + 2];
  }
  int ts = v.x + v.y + v.z + v.w;
  int s = ts;
#pragma unroll
  for (int off = 1; off < 64; off <<= 1) {
    int t = __shfl_up(s, off);
    if (lane >= off) s += t;
  }
  if (lane == 63) wsum[w] = s;
  __syncthreads();
  int wb = 0;
#pragma unroll
  for (int x = 0; x < 4; ++x)
    if (x < w) wb += wsum[x];
  int excl = s - ts + wb + partial[blockIdx.x];
  int o0 = excl, o1 = o0 + v.x, o2 = o1 + v.y, o3 = o2 + v.z;
  if (i0 + 3 < N) {
    int4 o = make_int4(o0, o1, o2, o3);
    *(int4*)(offsets + i0) = o;
    *(int4*)(cursor + i0) = o;
  } else {
    if (i0 < N) { offsets[i0] = o0; cursor[i0] = o0; }
    if (i0 + 1 < N) { offsets[i0 + 1] = o1; cursor[i0 + 1] = o1; }
    if (i0 + 2 < N) { offsets[i0 + 2] = o2; cursor[i0 + 2] = o2; }
  }
}

// ---- scatter edges into CSR (packed int2: src node, edge id) ----
__global__ void k_scatter(const int* __restrict__ src, const int* __restrict__ dstA,
                          int* __restrict__ cursor, int2* __restrict__ je, int E) {
  int e = blockIdx.x * blockDim.x + threadIdx.x;
  if (e >= E) return;
  int d = dstA[e];
  int p = atomicAdd(&cursor[d], 1);
  je[p] = make_int2(src[e], e);
}

__device__ __forceinline__ float bcastf(float v, int srclane) {
  return __int_as_float(__builtin_amdgcn_readlane(__float_as_int(v), srclane));
}

// ---- node linear: outa = hin@Wa + ba ; outb = hin@Wb + bb ----
__global__ __launch_bounds__(256, 1) void k_nodelin(
    const float* __restrict__ hin, const float* __restrict__ Wa,
    const float* __restrict__ ba, const float* __restrict__ Wb,
    const float* __restrict__ bb, float* __restrict__ outa, float* __restrict__ outb,
    int ostride, int astep, int N) {
  int lane = threadIdx.x & 63;
  int wave = blockIdx.x * (blockDim.x >> 6) + (threadIdx.x >> 6);
  int nwaves = gridDim.x * (blockDim.x >> 6);
  float wa[64], wb[64];
#pragma unroll
  for (int c = 0; c < 64; ++c) {
    wa[c] = Wa[c * 64 + lane];
    wb[c] = Wb[c * 64 + lane];
  }
  float bav = ba[lane], bbv = bb[lane];
  for (int i = wave; i < N; i += nwaves) {
    float h = hin[(size_t)i * 64 + lane];
    float a = bav, b = bbv;
#pragma unroll
    for (int c = 0; c < 64; ++c) {
      float hc = bcastf(h, c);
      a = fmaf(hc, wa[c], a);
      b = fmaf(hc, wb[c], b);
    }
    outa[(size_t)i * ostride + astep * lane] = a;
    outb[(size_t)i * ostride + astep * lane] = b;
  }
}

// ---- edge kernel: 8-deep inline-asm gather pipeline ----
// qv layout: row j = [q0,v0,q1,v1,...], stride 128; lane loads float2 at 2*lane.
// ISSUE: clamp slot to last valid edge (dup loads hit cache), mask in COMP.
#define ISSUE(U)                                                               \
  {                                                                            \
    int tt = t + U;                                                            \
    if (tt > mlast) tt = mlast;                                                \
    int j = __builtin_amdgcn_readlane(meta.x, tt);                             \
    eid##U = __builtin_amdgcn_readlane(meta.y, tt);                            \
    const float* ap = qv + ((size_t)j << 7) + (lane << 1);                     \
    asm volatile("global_load_dwordx2 %0, %1, off"                             \
                 : "=v"(qvr##U)                                                \
                 : "v"(ap));                                                   \
  }

#define COMP(U)                                                                \
  {                                                                            \
    const float4* ap = (const float4*)(ea + (size_t)eid##U * E_CH);            \
    float4 a0 = ap[0], a1 = ap[1], a2 = ap[2], a3 = ap[3];                     \
    float ev = 0.f;                                                            \
    ev = fmaf(a0.x, we[0], ev);   ev = fmaf(a0.y, we[1], ev);                  \
    ev = fmaf(a0.z, we[2], ev);   ev = fmaf(a0.w, we[3], ev);                  \
    ev = fmaf(a1.x, we[4], ev);   ev = fmaf(a1.y, we[5], ev);                  \
    ev = fmaf(a1.z, we[6], ev);   ev = fmaf(a1.w, we[7], ev);                  \
    ev = fmaf(a2.x, we[8], ev);   ev = fmaf(a2.y, we[9], ev);                  \
    ev = fmaf(a2.z, we[10], ev);  ev = fmaf(a2.w, we[11], ev);                 \
    ev = fmaf(a3.x, we[12], ev);  ev = fmaf(a3.y, we[13], ev);                 \
    ev = fmaf(a3.z, we[14], ev);  ev = fmaf(a3.w, we[15], ev);                 \
    float g = ki + qvr##U.x + ev;                                              \
    g = 1.0f / (1.0f + __expf(-g));                                            \
    g *= (t + U < m) ? 1.0f : 0.0f; /* mask clamped tail slots */              \
    acc = fmaf(g, qvr##U.y, acc);                                              \
  }

template <int MODE>
__global__ __launch_bounds__(256, 4) void k_edge(
    const int* __restrict__ offsets, const int2* __restrict__ je,
    const float* __restrict__ kk, const float* __restrict__ qv,
    const float* __restrict__ base, const float* __restrict__ ea,
    const float* __restrict__ We, const float* __restrict__ be,
    float* __restrict__ hnext, float* __restrict__ dout,
    const float* __restrict__ Wl, const float* __restrict__ bl, int N) {
  int lane = threadIdx.x & 63;
  int wave = blockIdx.x * (blockDim.x >> 6) + (threadIdx.x >> 6);
  int nwaves = gridDim.x * (blockDim.x >> 6);
  float we[16];
#pragma unroll
  for (int c = 0; c < 16; ++c) we[c] = We[c * 64 + lane];
  float bev = be[lane];
  float wl = (MODE == 2) ? Wl[lane] : 0.f;
  float bl0 = (MODE == 2) ? bl[0] : 0.f;
  for (int i = wave; i < N; i += nwaves) {
    float ki = kk[(size_t)i * 64 + lane] + bev;  // fold be into k_i
    float acc = base[(size_t)i * 64 + lane];
    int p0 = __builtin_amdgcn_readfirstlane(offsets[i]);
    int p1 = __builtin_amdgcn_readfirstlane(offsets[i + 1]);
    for (int pb = p0; pb < p1; pb += 64) {
      int m = p1 - pb;
      if (m > 64) m = 64;
      int mlast = m - 1;
      // cooperative CSR metadata load: one coalesced int2 per lane covers 64 edges
      int idx = pb + ((lane < m) ? lane : 0);
      int2 meta = je[idx];
      for (int t = 0; t < m; t += 8) {
        float2 qvr0, qvr1, qvr2, qvr3, qvr4, qvr5, qvr6, qvr7;
        int eid0, eid1, eid2, eid3, eid4, eid5, eid6, eid7;
        ISSUE(0) ISSUE(1) ISSUE(2) ISSUE(3)
        ISSUE(4) ISSUE(5) ISSUE(6) ISSUE(7)
        // drain the 8 gathers; "+v" outs make all consumers depend on this
        asm volatile("s_waitcnt vmcnt(0)"
                     : "+v"(qvr0), "+v"(qvr1), "+v"(qvr2), "+v"(qvr3),
                       "+v"(qvr4), "+v"(qvr5), "+v"(qvr6), "+v"(qvr7));
        __builtin_amdgcn_sched_barrier(0);
        COMP(0) COMP(1) COMP(2) COMP(3)
        COMP(4) COMP(5) COMP(6) COMP(7)
      }
    }
    float r = (acc > 0.f) ? acc : expm1f(acc);  // elu
    if (MODE == 0) {
      hnext[(size_t)i * 64 + lane] = r;
    } else if (MODE == 1) {
      hnext[(size_t)i * 64 + lane] = r;
      dout[(size_t)N + (size_t)i * 64 + lane] = r;       // feat block
      dout[(size_t)N * 65 + (size_t)i * 65 + lane] = r;  // concat block
    } else {
      float dot = r * wl;
#pragma unroll
      for (int m2 = 32; m2 >= 1; m2 >>= 1) dot += __shfl_xor(dot, m2);
      float logit = dot + bl0;
      if (lane == 0) {
        dout[i] = 1.0f / (1.0f + __expf(-logit));
        dout[(size_t)N * 65 + (size_t)i * 65 + 64] = logit;  // raw logit col
      }
    }
  }
}

extern "C" void kernel_launch(void* const* d_in, const int* in_sizes, int n_in,
                              void* d_out, int out_size, void* d_ws, size_t ws_size,
                              hipStream_t stream) {
  const float* x   = (const float*)d_in[0];
  const void*  ei  = d_in[1];
  const float* ea  = (const float*)d_in[2];
  const float* Wk  = (const float*)d_in[3];
  const float* bk  = (const float*)d_in[4];
  const float* Wq  = (const float*)d_in[5];
  const float* bq  = (const float*)d_in[6];
  const float* Wv  = (const float*)d_in[7];
  const float* bv  = (const float*)d_in[8];
  const float* We  = (const float*)d_in[9];
  const float* be  = (const float*)d_in[10];
  const float* Ws  = (const float*)d_in[11];
  const float* bia = (const float*)d_in[12];
  const float* Wl  = (const float*)d_in[13];
  const float* bl  = (const float*)d_in[14];
  int N = in_sizes[0] / D_CH;
  int E = in_sizes[2] / E_CH;
  int NB = (N + 1023) / 1024;

  char* w = (char*)d_ws;
  auto alloc = [&](size_t bytes) -> char* {
    char* r = w;
    w += (bytes + 255) & ~(size_t)255;
    return r;
  };
  int* flag     = (int*)alloc(16);
  int* src      = (int*)alloc((size_t)E * 4);
  int* dstA     = (int*)alloc((size_t)E * 4);
  int* deg      = (int*)alloc((size_t)N * 4);
  int* partial  = (int*)alloc((size_t)NB * 4);
  int* offsets  = (int*)alloc((size_t)(N + 1) * 4);
  int* cursor   = (int*)alloc((size_t)N * 4);
  int2* je      = (int2*)alloc((size_t)E * 8);
  float* kk     = (float*)alloc((size_t)N * D_CH * 4);
  float* qv     = (float*)alloc((size_t)N * 128 * 4);
  float* baseb  = (float*)alloc((size_t)N * D_CH * 4);
  float* h1     = (float*)alloc((size_t)N * D_CH * 4);
  float* feat   = (float*)alloc((size_t)N * D_CH * 4);
  float* dout   = (float*)d_out;

  int gE = (E + 255) / 256;
  int gN = (N + 255) / 256;

  k_prep<<<gN, 256, 0, stream>>>((const unsigned int*)ei, flag, deg, N, 8192);
  k_normhist<<<gE, 256, 0, stream>>>(ei, flag, src, dstA, deg, E);
  k_scanpart<<<NB, 256, 0, stream>>>(deg, partial, N);
  k_scanroot<<<1, 64, 0, stream>>>(partial, offsets, NB, N);
  k_scanapply<<<NB, 256, 0, stream>>>(deg, partial, offsets, cursor, N);
  k_scatter<<<gE, 256, 0, stream>>>(src, dstA, cursor, je, E);

  const float* hin = x;
  for (int l = 0; l < 3; ++l) {
    const float* Wk_l = Wk + (size_t)l * 4096;
    const float* bk_l = bk + (size_t)l * 64;
    const float* Wq_l = Wq + (size_t)l * 4096;
    const float* bq_l = bq + (size_t)l * 64;
    const float* Wv_l = Wv + (size_t)l * 4096;
    const float* bv_l = bv + (size_t)l * 64;
    const float* We_l = We + (size_t)l * 1024;
    const float* be_l = be + (size_t)l * 64;
    const float* Ws_l = Ws + (size_t)l * 4096;
    const float* bi_l = bia + (size_t)l * 64;

    // k and skip-base (stride 64, step 1); q and v channel-interleaved in qv
    // (stride 128, step 2, v at +1)
    k_nodelin<<<1024, 256, 0, stream>>>(hin, Wk_l, bk_l, Ws_l, bi_l, kk, baseb,
                                        64, 1, N);
    k_nodelin<<<1024, 256, 0, stream>>>(hin, Wq_l, bq_l, Wv_l, bv_l, qv, qv + 1,
                                        128, 2, N);
    if (l == 0) {
      k_edge<0><<<2048, 256, 0, stream>>>(offsets, je, kk, qv, baseb, ea, We_l, be_l,
                                          h1, dout, Wl, bl, N);
      hin = h1;
    } else if (l == 1) {
      k_edge<1><<<2048, 256, 0, stream>>>(offsets, je, kk, qv, baseb, ea, We_l, be_l,
                                          feat, dout, Wl, bl, N);
      hin = feat;
    } else {
      k_edge<2><<<2048, 256, 0, stream>>>(offsets, je, kk, qv, baseb, ea, We_l, be_l,
                                          h1, dout, Wl, bl, N);
    }
  }
}